// Round 12
// baseline (474.449 us; speedup 1.0000x reference)
//
#include <hip/hip_runtime.h>
#include <hip/hip_bf16.h>

#define NEx 32
#define QKVN 1536
#define MAXTILES 96

typedef __attribute__((ext_vector_type(4))) float f32x4_t;
typedef __attribute__((ext_vector_type(8))) __bf16 bf16x8_t;

__device__ __forceinline__ unsigned short f2bfu(float f) {
  union { float f; unsigned int u; } a; a.f = f;
  unsigned int r = a.u + 0x7fffu + ((a.u >> 16) & 1u);
  return (unsigned short)(r >> 16);
}
__device__ __forceinline__ float bf2f(unsigned short u) {
  union { unsigned int u; float f; } a; a.u = ((unsigned int)u) << 16; return a.f;
}
__device__ __forceinline__ uint2 pack4u(unsigned short a, unsigned short b,
                                        unsigned short c, unsigned short d) {
  return make_uint2((unsigned int)a | ((unsigned int)b << 16),
                    (unsigned int)c | ((unsigned int)d << 16));
}
__device__ __forceinline__ void split2(float v, unsigned short& hi, unsigned short& lo) {
  hi = f2bfu(v);
  lo = f2bfu(v - bf2f(hi));
}
// async global->LDS, 16B per lane; lds dest = wave-uniform base + lane*16
typedef const __attribute__((address_space(1))) void* gas_t;
typedef __attribute__((address_space(3))) void* las_t;
__device__ __forceinline__ void gl16(const void* g, void* l) {
  __builtin_amdgcn_global_load_lds((gas_t)g, (las_t)l, 16, 0, 0);
}

// ---------- RoPE sin/cos table: [2048][32] each ----------
__global__ __launch_bounds__(256) void k_ropetab(float* __restrict__ cost,
    float* __restrict__ sint) {
  int idx = blockIdx.x * 256 + threadIdx.x;   // 2048*32
  int i = idx & 31, t = idx >> 5;
  float invf = exp2f(-(float)i * (17.194602975157967f / 32.f));
  float ang = ((float)t * (1.f / 32.f)) * invf;
  float s, c;
  sincosf(ang, &s, &c);
  cost[idx] = c;
  sint[idx] = s;
}

// ---------- weight transpose(+convert) prepass: fp32 [E][K=1024][N] -> bf16 [E][N][1024] ----------
template<int SPLIT>
__global__ __launch_bounds__(256) void k_wT(const float* __restrict__ in,
    unsigned short* __restrict__ outh, unsigned short* __restrict__ outl, int N) {
  __shared__ float T[64][68];
  int k0 = blockIdx.x * 64, n0 = blockIdx.y * 64, e = blockIdx.z;
  const float* src = in + (size_t)e * 1024 * N;
  int t = threadIdx.x;
  int rk = t >> 2, c4 = (t & 3) * 4;
#pragma unroll
  for (int j = 0; j < 4; ++j) {
    int col = c4 + j * 16;
    f32x4_t v = *(const f32x4_t*)(src + (size_t)(k0 + rk) * N + n0 + col);
    *(f32x4_t*)&T[rk][col] = v;
  }
  __syncthreads();
  int nn = t >> 2, kc0 = (t & 3) * 16;
  size_t orow = ((size_t)e * N + n0 + nn) * 1024 + k0;
#pragma unroll
  for (int j = 0; j < 2; ++j) {
    int kc = kc0 + j * 8;
    unsigned short hi[8], lo[8];
#pragma unroll
    for (int q = 0; q < 8; ++q) split2(T[kc + q][nn], hi[q], lo[q]);
    uint2 a = pack4u(hi[0], hi[1], hi[2], hi[3]);
    uint2 b = pack4u(hi[4], hi[5], hi[6], hi[7]);
    *(uint4*)(outh + orow + kc) = make_uint4(a.x, a.y, b.x, b.y);
    if (SPLIT) {
      uint2 c = pack4u(lo[0], lo[1], lo[2], lo[3]);
      uint2 d = pack4u(lo[4], lo[5], lo[6], lo[7]);
      *(uint4*)(outl + orow + kc) = make_uint4(c.x, c.y, d.x, d.y);
    }
  }
}

// ---------- RMSNorm -> bf16 hi/lo planes ----------
__global__ __launch_bounds__(256) void k_rmsnorm_s(const float* __restrict__ x,
    const float* __restrict__ w, unsigned short* __restrict__ ph, unsigned short* __restrict__ pl) {
  int row = blockIdx.x, tid = threadIdx.x;
  f32x4_t v = *(const f32x4_t*)(x + (size_t)row * 1024 + tid * 4);
  float ss = v.x * v.x + v.y * v.y + v.z * v.z + v.w * v.w;
#pragma unroll
  for (int o = 32; o > 0; o >>= 1) ss += __shfl_xor(ss, o);
  __shared__ float red[4];
  if ((tid & 63) == 0) red[tid >> 6] = ss;
  __syncthreads();
  float sc = rsqrtf((red[0] + red[1] + red[2] + red[3]) * (1.f / 1024.f) + 1e-5f);
  const float* wr = w + tid * 4;
  ushort4 h4, l4;
  split2(v.x * sc * wr[0], h4.x, l4.x);
  split2(v.y * sc * wr[1], h4.y, l4.y);
  split2(v.z * sc * wr[2], h4.z, l4.z);
  split2(v.w * sc * wr[3], h4.w, l4.w);
  *(ushort4*)(ph + (size_t)row * 1024 + tid * 4) = h4;
  *(ushort4*)(pl + (size_t)row * 1024 + tid * 4) = l4;
}

// ---------- RMSNorm -> fp32 + bf16; seeds out = x1; zeroes cnt ----------
__global__ __launch_bounds__(256) void k_rmsnorm_f(const float* __restrict__ x,
    const float* __restrict__ w, float* __restrict__ outf, unsigned short* __restrict__ outb,
    float* __restrict__ out, int* __restrict__ cnt) {
  int row = blockIdx.x, tid = threadIdx.x;
  if (row == 0 && tid < NEx) cnt[tid] = 0;
  f32x4_t v = *(const f32x4_t*)(x + (size_t)row * 1024 + tid * 4);
  *(f32x4_t*)(out + (size_t)row * 1024 + tid * 4) = v;   // out = x1; moe_down accumulates
  float ss = v.x * v.x + v.y * v.y + v.z * v.z + v.w * v.w;
#pragma unroll
  for (int o = 32; o > 0; o >>= 1) ss += __shfl_xor(ss, o);
  __shared__ float red[4];
  if ((tid & 63) == 0) red[tid >> 6] = ss;
  __syncthreads();
  float sc = rsqrtf((red[0] + red[1] + red[2] + red[3]) * (1.f / 1024.f) + 1e-5f);
  const float* wr = w + tid * 4;
  f32x4_t o4;
  o4.x = v.x * sc * wr[0]; o4.y = v.y * sc * wr[1];
  o4.z = v.z * sc * wr[2]; o4.w = v.w * sc * wr[3];
  *(f32x4_t*)(outf + (size_t)row * 1024 + tid * 4) = o4;
  ushort4 b4;
  b4.x = f2bfu(o4.x); b4.y = f2bfu(o4.y); b4.z = f2bfu(o4.z); b4.w = f2bfu(o4.w);
  *(ushort4*)(outb + (size_t)row * 1024 + tid * 4) = b4;
}

// ---------- split-plane GEMM (fp32-accurate): C = A @ B^T + bias (+res) ----------
template<int RES>
__global__ __launch_bounds__(256) void k_gemm_s(
    const unsigned short* __restrict__ Ahg, const unsigned short* __restrict__ Alg,
    const unsigned short* __restrict__ BhT, const unsigned short* __restrict__ BlT,
    const float* __restrict__ bias, const float* __restrict__ res,
    float* __restrict__ C, int N) {
  __shared__ unsigned short Ah[64 * 32], Al[64 * 32], Bh[128 * 32], Bl[128 * 32];
  int tid = threadIdx.x, lane = tid & 63, w = tid >> 6;
  int m0 = blockIdx.y * 64, n0 = blockIdx.x * 128;
  int wm = (w >> 1) * 32, wn = (w & 1) * 64;
  int rl = lane >> 2, koff = (lane & 3) * 8;
  const unsigned short* agh = Ahg + (size_t)(m0 + w * 16 + rl) * 1024 + koff;
  const unsigned short* agl = Alg + (size_t)(m0 + w * 16 + rl) * 1024 + koff;
  const unsigned short* bgh0 = BhT + (size_t)(n0 + (w * 2 + 0) * 16 + rl) * 1024 + koff;
  const unsigned short* bgh1 = BhT + (size_t)(n0 + (w * 2 + 1) * 16 + rl) * 1024 + koff;
  const unsigned short* bgl0 = BlT + (size_t)(n0 + (w * 2 + 0) * 16 + rl) * 1024 + koff;
  const unsigned short* bgl1 = BlT + (size_t)(n0 + (w * 2 + 1) * 16 + rl) * 1024 + koff;
  f32x4_t acc[2][4];
#pragma unroll
  for (int i = 0; i < 2; ++i)
#pragma unroll
    for (int j = 0; j < 4; ++j) acc[i][j] = (f32x4_t){0.f, 0.f, 0.f, 0.f};
  int fr = lane & 15, fc = (lane >> 4) * 8;
  for (int k0 = 0; k0 < 1024; k0 += 32) {
    gl16(agh + k0, (char*)Ah + w * 1024);
    gl16(agl + k0, (char*)Al + w * 1024);
    gl16(bgh0 + k0, (char*)Bh + (w * 2 + 0) * 1024);
    gl16(bgh1 + k0, (char*)Bh + (w * 2 + 1) * 1024);
    gl16(bgl0 + k0, (char*)Bl + (w * 2 + 0) * 1024);
    gl16(bgl1 + k0, (char*)Bl + (w * 2 + 1) * 1024);
    __syncthreads();
    bf16x8_t fah[2], fal[2], fbh[4], fbl[4];
#pragma unroll
    for (int mi = 0; mi < 2; ++mi) {
      fah[mi] = *(const bf16x8_t*)(Ah + (wm + mi * 16 + fr) * 32 + fc);
      fal[mi] = *(const bf16x8_t*)(Al + (wm + mi * 16 + fr) * 32 + fc);
    }
#pragma unroll
    for (int nj = 0; nj < 4; ++nj) {
      fbh[nj] = *(const bf16x8_t*)(Bh + (wn + nj * 16 + fr) * 32 + fc);
      fbl[nj] = *(const bf16x8_t*)(Bl + (wn + nj * 16 + fr) * 32 + fc);
    }
#pragma unroll
    for (int mi = 0; mi < 2; ++mi)
#pragma unroll
      for (int nj = 0; nj < 4; ++nj) {
        acc[mi][nj] = __builtin_amdgcn_mfma_f32_16x16x32_bf16(fah[mi], fbh[nj], acc[mi][nj], 0, 0, 0);
        acc[mi][nj] = __builtin_amdgcn_mfma_f32_16x16x32_bf16(fah[mi], fbl[nj], acc[mi][nj], 0, 0, 0);
        acc[mi][nj] = __builtin_amdgcn_mfma_f32_16x16x32_bf16(fal[mi], fbh[nj], acc[mi][nj], 0, 0, 0);
      }
    __syncthreads();
  }
  int frow = (lane >> 4) * 4;
#pragma unroll
  for (int mi = 0; mi < 2; ++mi)
#pragma unroll
    for (int nj = 0; nj < 4; ++nj) {
      int col = n0 + wn + nj * 16 + fr;
      float bv = bias[col];
#pragma unroll
      for (int r = 0; r < 4; ++r) {
        int row = m0 + wm + mi * 16 + frow + r;
        float v = acc[mi][nj][r] + bv;
        if (RES) v += res[(size_t)row * N + col];
        C[(size_t)row * N + col] = v;
      }
    }
}

// ---------- sliding-window attention with sink; RoPE fused via table; fused 4-query loops ----------
__global__ __launch_bounds__(256) void k_attn(const float* __restrict__ qkv,
    const float* __restrict__ cost, const float* __restrict__ sint,
    const float* __restrict__ sink, unsigned short* __restrict__ yh,
    unsigned short* __restrict__ yl) {
  __shared__ float Kl[72 * 65];
  __shared__ float Vl[72 * 64];
  __shared__ float ql[16][64];
  __shared__ float pl[4][4][128];   // [wave][qq][slot] — wave-private, no barriers needed
  int i0 = blockIdx.x * 16, hh = blockIdx.y;
  int g = hh >> 2;
  int jb = i0 - 128; if (jb < 0) jb = 0;
  int nk = i0 + 16 - jb;
  int tid = threadIdx.x, wid = tid >> 6, lane = tid & 63;
  {
    int r = tid >> 4, d4 = (tid & 15) * 4;
    int t = i0 + r;
    f32x4_t qv = *(const f32x4_t*)(qkv + (size_t)t * QKVN + hh * 64 + d4);
    float2 cs = *(const float2*)&cost[t * 32 + (d4 >> 1)];
    float2 sn = *(const float2*)&sint[t * 32 + (d4 >> 1)];
    f32x4_t qr;
    qr.x = qv.x * cs.x - qv.y * sn.x; qr.y = qv.x * sn.x + qv.y * cs.x;
    qr.z = qv.z * cs.y - qv.w * sn.y; qr.w = qv.z * sn.y + qv.w * cs.y;
    *(f32x4_t*)&ql[r][d4] = qr;
  }
  float sk = sink[hh];
  float m_[4], s_[4], y_[4];
#pragma unroll
  for (int qq = 0; qq < 4; ++qq) { m_[qq] = sk; s_[qq] = 0.f; y_[qq] = 0.f; }
  int nch = (nk + 71) / 72;
  int cbase = 0;
  int qb = wid * 4;
  for (int ch = 0; ch < nch; ++ch) {
    int csz = nk - cbase; if (csz > 72) csz = 72;
    __syncthreads();
    for (int id = tid; id < csz * 16; id += 256) {
      int c = id >> 4, d4 = (id & 15) * 4;
      int t = jb + cbase + c;
      const float* kp = qkv + (size_t)t * QKVN + 1024 + g * 64 + d4;
      f32x4_t kv = *(const f32x4_t*)kp;
      float2 cs = *(const float2*)&cost[t * 32 + (d4 >> 1)];
      float2 sn = *(const float2*)&sint[t * 32 + (d4 >> 1)];
      f32x4_t kr;
      kr.x = kv.x * cs.x - kv.y * sn.x; kr.y = kv.x * sn.x + kv.y * cs.x;
      kr.z = kv.z * cs.y - kv.w * sn.y; kr.w = kv.z * sn.y + kv.w * cs.y;
      *(f32x4_t*)&Kl[c * 65 + d4] = kr;
      *(f32x4_t*)&Vl[c * 64 + d4] = *(const f32x4_t*)(kp + 256);
    }
    __syncthreads();
    int s1 = lane + 64;
    int r1 = (s1 < csz) ? s1 : (csz - 1);
    const float* k0p = Kl + lane * 65;
    const float* k1p = Kl + r1 * 65;
    float a0[4] = {0.f, 0.f, 0.f, 0.f}, a1[4] = {0.f, 0.f, 0.f, 0.f};
#pragma unroll 4
    for (int d = 0; d < 64; ++d) {
      float k0 = k0p[d], k1 = k1p[d];
#pragma unroll
      for (int qq = 0; qq < 4; ++qq) {
        float qd = ql[qb + qq][d];
        a0[qq] += qd * k0;
        a1[qq] += qd * k1;
      }
    }
    int c0 = cbase + lane, c1 = cbase + s1;
    float fac_[4];
#pragma unroll
    for (int qq = 0; qq < 4; ++qq) {
      int cm = i0 + qb + qq - jb;
      bool ok0 = (lane < csz) && (c0 <= cm) && (c0 >= cm - 128);
      bool ok1 = (s1 < csz) && (c1 <= cm) && (c1 >= cm - 128);
      float l0 = ok0 ? a0[qq] * 0.125f : -1e30f;
      float l1 = ok1 ? a1[qq] * 0.125f : -1e30f;
      float mc = fmaxf(l0, l1);
#pragma unroll
      for (int o = 32; o > 0; o >>= 1) mc = fmaxf(mc, __shfl_xor(mc, o));
      float mo = m_[qq];
      float mn = fmaxf(mo, mc);
      float fac = __expf(mo - mn);
      float p0 = __expf(l0 - mn), p1 = __expf(l1 - mn);
      float ps = p0 + p1;
#pragma unroll
      for (int o = 32; o > 0; o >>= 1) ps += __shfl_xor(ps, o);
      m_[qq] = mn;
      s_[qq] = s_[qq] * fac + ps;
      pl[wid][qq][lane] = p0;
      pl[wid][qq][s1] = p1;
      fac_[qq] = fac;
    }
#pragma unroll
    for (int qq = 0; qq < 4; ++qq) y_[qq] *= fac_[qq];
    for (int s = 0; s < csz; ++s) {
      float v = Vl[s * 64 + lane];
      y_[0] += pl[wid][0][s] * v;
      y_[1] += pl[wid][1][s] * v;
      y_[2] += pl[wid][2][s] * v;
      y_[3] += pl[wid][3][s] * v;
    }
    cbase += csz;
  }
#pragma unroll
  for (int qq = 0; qq < 4; ++qq) {
    float inv = 1.f / (s_[qq] + __expf(sk - m_[qq]));
    int i = i0 + qb + qq;
    unsigned short hi, lo;
    split2(y_[qq] * inv, hi, lo);
    yh[(size_t)i * 1024 + hh * 64 + lane] = hi;
    yl[(size_t)i * 1024 + hh * 64 + lane] = lo;
  }
}

// ---------- gate + top4 + softmax (fp32); fused expert counting ----------
__global__ __launch_bounds__(64) void k_gate(const float* __restrict__ h2f,
    const float* __restrict__ gw, const float* __restrict__ gb,
    int* __restrict__ texp, float* __restrict__ twt, int* __restrict__ cnt) {
  int t = blockIdx.x, l = threadIdx.x;
  int e = l & 31, half = l >> 5;
  const float* hr = h2f + (size_t)t * 1024 + half * 512;
  const float* wp = gw + (size_t)half * 512 * 32 + e;
  float s = 0;
  for (int d = 0; d < 512; ++d) s += hr[d] * wp[(size_t)d * 32];
  s += __shfl_xor(s, 32);
  __shared__ float gl[32];
  if (l < 32) gl[l] = s + gb[e];
  __syncthreads();
  if (l == 0) {
    int bi[4]; float bv[4];
    for (int j = 0; j < 4; ++j) {
      int mi_ = 0; float mv = gl[0];
      for (int q = 1; q < 32; ++q) if (gl[q] > mv) { mv = gl[q]; mi_ = q; }
      bi[j] = mi_; bv[j] = mv; gl[mi_] = -1e30f;
    }
    float mx = bv[0], sum = 0, wv[4];
    for (int j = 0; j < 4; ++j) { wv[j] = __expf(bv[j] - mx); sum += wv[j]; }
    float inv = 1.f / sum;
    for (int j = 0; j < 4; ++j) {
      texp[t * 4 + j] = bi[j];
      twt[t * 4 + j] = wv[j] * inv;
      atomicAdd(&cnt[bi[j]], 1);
    }
  }
}

__global__ void k_moe_off(const int* __restrict__ cnt, int* __restrict__ off,
                          int* __restrict__ tiles) {
  if (threadIdx.x == 0) {
    int s = 0, t = 0;
    for (int e = 0; e < NEx; ++e) {
      off[e] = s;
      int nt = (cnt[e] + 127) >> 7;
      for (int j = 0; j < nt; ++j) tiles[t++] = e | (j << 8);
      s += cnt[e];
    }
    for (; t < MAXTILES; ++t) tiles[t] = -1;
  }
}

__global__ __launch_bounds__(256) void k_moe_assign(const int* __restrict__ texp,
    const float* __restrict__ twt, const int* __restrict__ off,
    int* __restrict__ slot_token, float* __restrict__ slot_wt) {
  int e = blockIdx.x, tid = threadIdx.x;
  int b0 = tid * 32;
  int c = 0;
  for (int i = 0; i < 32; ++i) c += (texp[b0 + i] == e);
  __shared__ int pre[256];
  pre[tid] = c;
  __syncthreads();
  for (int d = 1; d < 256; d <<= 1) {
    int v = (tid >= d) ? pre[tid - d] : 0;
    __syncthreads();
    pre[tid] += v;
    __syncthreads();
  }
  int run = off[e] + pre[tid] - c;
  for (int i = 0; i < 32; ++i) {
    int idx = b0 + i;
    if (texp[idx] == e) {
      slot_token[run] = idx >> 2;
      slot_wt[run] = twt[idx];
      ++run;
    }
  }
}

// ---------- MoE up: bf16 x bf16^T, gl16 staging (round-10 structure) ----------
__global__ __launch_bounds__(256) void k_moe_up(const unsigned short* __restrict__ h2b,
    const unsigned short* __restrict__ WupT, const int* __restrict__ cnt,
    const int* __restrict__ off, const int* __restrict__ tiles,
    const int* __restrict__ slot_token, unsigned short* __restrict__ act) {
  int code = tiles[blockIdx.y];
  if (code < 0) return;
  int e = code & 255;
  int m0 = (code >> 8) << 7;
  int ne = cnt[e];
  int n0 = blockIdx.x * 64;
  int base = off[e];
  __shared__ unsigned short Asm[128 * 32];
  __shared__ unsigned short Bsm[128 * 32];
  int tid = threadIdx.x, lane = tid & 63, w = tid >> 6;
  int rl = lane >> 2, koff = (lane & 3) * 8;
  const unsigned short* ag[2];
  const unsigned short* bg[2];
#pragma unroll
  for (int i = 0; i < 2; ++i) {
    int row = (w * 2 + i) * 16 + rl;
    int tok = (m0 + row < ne) ? slot_token[base + m0 + row] : 0;
    ag[i] = h2b + (size_t)tok * 1024 + koff;
    int grow = (row < 64) ? (n0 + row) : (1024 + n0 + row - 64);
    bg[i] = WupT + (size_t)e * 2048 * 1024 + (size_t)grow * 1024 + koff;
  }
  f32x4_t acc[2][8];
#pragma unroll
  for (int i = 0; i < 2; ++i)
#pragma unroll
    for (int j = 0; j < 8; ++j) acc[i][j] = (f32x4_t){0.f, 0.f, 0.f, 0.f};
  int fr = lane & 15, fc = (lane >> 4) * 8;
  for (int k0 = 0; k0 < 1024; k0 += 32) {
    gl16(ag[0] + k0, (char*)Asm + (w * 2 + 0) * 1024);
    gl16(ag[1] + k0, (char*)Asm + (w * 2 + 1) * 1024);
    gl16(bg[0] + k0, (char*)Bsm + (w * 2 + 0) * 1024);
    gl16(bg[1] + k0, (char*)Bsm + (w * 2 + 1) * 1024);
    __syncthreads();
    bf16x8_t af[2], bfr[8];
#pragma unroll
    for (int mi = 0; mi < 2; ++mi)
      af[mi] = *(const bf16x8_t*)(Asm + (w * 32 + mi * 16 + fr) * 32 + fc);
#pragma unroll
    for (int nj = 0; nj < 8; ++nj)
      bfr[nj] = *(const bf16x8_t*)(Bsm + (nj * 16 + fr) * 32 + fc);
#pragma unroll
    for (int mi = 0; mi < 2; ++mi)
#pragma unroll
      for (int nj = 0; nj < 8; ++nj)
        acc[mi][nj] = __builtin_amdgcn_mfma_f32_16x16x32_bf16(af[mi], bfr[nj], acc[mi][nj], 0, 0, 0);
    __syncthreads();
  }
  int frow = (lane >> 4) * 4;
#pragma unroll
  for (int mi = 0; mi < 2; ++mi)
#pragma unroll
    for (int r = 0; r < 4; ++r) {
      int row = m0 + w * 32 + mi * 16 + frow + r;
      if (row < ne) {
#pragma unroll
        for (int nj = 0; nj < 4; ++nj) {
          float u = acc[mi][nj][r];
          float gg = acc[mi][nj + 4][r];
          float sig = 1.f / (1.f + __expf(-gg));
          act[(size_t)(base + row) * 1024 + n0 + nj * 16 + fr] = f2bfu(u * gg * sig);
        }
      }
    }
}

// ---------- MoE down: bf16 x bf16^T, gl16 staging, atomic scatter into OUT ----------
__global__ __launch_bounds__(256) void k_moe_down(const unsigned short* __restrict__ act,
    const unsigned short* __restrict__ WdnT, const int* __restrict__ cnt,
    const int* __restrict__ off, const int* __restrict__ tiles,
    const int* __restrict__ slot_token, const float* __restrict__ slot_wt,
    float* __restrict__ out) {
  int code = tiles[blockIdx.y];
  if (code < 0) return;
  int e = code & 255;
  int m0 = (code >> 8) << 7;
  int ne = cnt[e];
  int n0 = blockIdx.x * 128;
  int base = off[e];
  __shared__ unsigned short Asm[128 * 32];
  __shared__ unsigned short Bsm[128 * 32];
  int tid = threadIdx.x, lane = tid & 63, w = tid >> 6;
  int wm = (w >> 1) * 64, wn = (w & 1) * 64;
  int rl = lane >> 2, koff = (lane & 3) * 8;
  const unsigned short* ag[2];
  const unsigned short* bg[2];
#pragma unroll
  for (int i = 0; i < 2; ++i) {
    int row = (w * 2 + i) * 16 + rl;
    ag[i] = act + (size_t)(base + m0 + row) * 1024 + koff;  // act padded, OOB rows safe
    bg[i] = WdnT + (size_t)e * 1024 * 1024 + (size_t)(n0 + row) * 1024 + koff;
  }
  f32x4_t acc[4][4];
#pragma unroll
  for (int i = 0; i < 4; ++i)
#pragma unroll
    for (int j = 0; j < 4; ++j) acc[i][j] = (f32x4_t){0.f, 0.f, 0.f, 0.f};
  int fr = lane & 15, fc = (lane >> 4) * 8;
  for (int k0 = 0; k0 < 1024; k0 += 32) {
    gl16(ag[0] + k0, (char*)Asm + (w * 2 + 0) * 1024);
    gl16(ag[1] + k0, (char*)Asm + (w * 2 + 1) * 1024);
    gl16(bg[0] + k0, (char*)Bsm + (w * 2 + 0) * 1024);
    gl16(bg[1] + k0, (char*)Bsm + (w * 2 + 1) * 1024);
    __syncthreads();
    bf16x8_t af[4], bfr[4];
#pragma unroll
    for (int mi = 0; mi < 4; ++mi)
      af[mi] = *(const bf16x8_t*)(Asm + (wm + mi * 16 + fr) * 32 + fc);
#pragma unroll
    for (int nj = 0; nj < 4; ++nj)
      bfr[nj] = *(const bf16x8_t*)(Bsm + (wn + nj * 16 + fr) * 32 + fc);
#pragma unroll
    for (int mi = 0; mi < 4; ++mi)
#pragma unroll
      for (int nj = 0; nj < 4; ++nj)
        acc[mi][nj] = __builtin_amdgcn_mfma_f32_16x16x32_bf16(af[mi], bfr[nj], acc[mi][nj], 0, 0, 0);
    __syncthreads();
  }
  int frow = (lane >> 4) * 4;
#pragma unroll
  for (int mi = 0; mi < 4; ++mi)
#pragma unroll
    for (int r = 0; r < 4; ++r) {
      int row = m0 + wm + mi * 16 + frow + r;
      if (row < ne) {
        int slot = base + row;
        int token = slot_token[slot];
        float wt = slot_wt[slot];
#pragma unroll
        for (int nj = 0; nj < 4; ++nj) {
          int col = n0 + wn + nj * 16 + fr;
          atomicAdd(&out[(size_t)token * 1024 + col], wt * acc[mi][nj][r]);
        }
      }
    }
}

extern "C" void kernel_launch(void* const* d_in, const int* in_sizes, int n_in,
                              void* d_out, int out_size, void* d_ws, size_t ws_size,
                              hipStream_t stream) {
  const float* x           = (const float*)d_in[0];
  const float* attn_norm_w = (const float*)d_in[1];
  const float* ffn_norm_w  = (const float*)d_in[2];
  const float* qkv_w       = (const float*)d_in[3];
  const float* qkv_b       = (const float*)d_in[4];
  const float* proj_w      = (const float*)d_in[5];
  const float* proj_b      = (const float*)d_in[6];
  const float* attn_sink   = (const float*)d_in[7];
  const float* gate_w      = (const float*)d_in[8];
  const float* gate_b      = (const float*)d_in[9];
  const float* W_up        = (const float*)d_in[10];
  const float* W_down      = (const float*)d_in[11];
  float* out = (float*)d_out;

  char* ws = (char*)d_ws;
  size_t o = 0;
  auto alloc = [&](size_t bytes) -> void* {
    void* p = ws + o;
    o = (o + bytes + 255) & ~(size_t)255;
    return p;
  };
  unsigned short* WT      = (unsigned short*)alloc((size_t)32 * 2048 * 1024 * 2); // WupT then WdnT
  unsigned short* qkvThi  = (unsigned short*)alloc((size_t)1536 * 1024 * 2);
  unsigned short* qkvTlo  = (unsigned short*)alloc((size_t)1536 * 1024 * 2);
  unsigned short* projThi = (unsigned short*)alloc((size_t)1024 * 1024 * 2);
  unsigned short* projTlo = (unsigned short*)alloc((size_t)1024 * 1024 * 2);
  unsigned short* pAhi    = (unsigned short*)alloc((size_t)2048 * 1024 * 2);  // h planes, then y planes
  unsigned short* pAlo    = (unsigned short*)alloc((size_t)2048 * 1024 * 2);
  float* qkv              = (float*)alloc((size_t)2048 * 1536 * 4);           // later h2f(8MB)+h2b(4MB)
  float* x1               = (float*)alloc((size_t)2048 * 1024 * 4);
  unsigned short* act     = (unsigned short*)alloc((size_t)(8192 + 128) * 1024 * 2);
  float* cost             = (float*)alloc((size_t)2048 * 32 * 4);
  float* sint             = (float*)alloc((size_t)2048 * 32 * 4);
  int* texp               = (int*)alloc(8192 * 4);
  float* twt              = (float*)alloc(8192 * 4);
  int* cnt                = (int*)alloc(256);
  int* offs               = (int*)alloc(256);
  int* tiles              = (int*)alloc(MAXTILES * 4);
  int* slot_token         = (int*)alloc(8192 * 4);
  float* slot_wt          = (float*)alloc(8192 * 4);
  float* h2f              = qkv;                                   // qkv dead after attn
  unsigned short* h2b     = (unsigned short*)(qkv + (size_t)2048 * 1024);

  // rope table + weight prepass (qkv/proj split planes; W_up bf16 transposed)
  k_ropetab<<<256, 256, 0, stream>>>(cost, sint);
  k_wT<1><<<dim3(16, 24, 1), 256, 0, stream>>>(qkv_w, qkvThi, qkvTlo, 1536);
  k_wT<1><<<dim3(16, 16, 1), 256, 0, stream>>>(proj_w, projThi, projTlo, 1024);
  k_wT<0><<<dim3(16, 32, 32), 256, 0, stream>>>(W_up, WT, nullptr, 2048);

  k_rmsnorm_s<<<2048, 256, 0, stream>>>(x, attn_norm_w, pAhi, pAlo);
  k_gemm_s<0><<<dim3(12, 32), 256, 0, stream>>>(pAhi, pAlo, qkvThi, qkvTlo, qkv_b, nullptr, qkv, 1536);
  k_attn<<<dim3(128, 16), 256, 0, stream>>>(qkv, cost, sint, attn_sink, pAhi, pAlo);
  k_gemm_s<1><<<dim3(8, 32), 256, 0, stream>>>(pAhi, pAlo, projThi, projTlo, proj_b, x, x1, 1024);
  k_rmsnorm_f<<<2048, 256, 0, stream>>>(x1, ffn_norm_w, h2f, h2b, out, cnt);
  k_gate<<<2048, 64, 0, stream>>>(h2f, gate_w, gate_b, texp, twt, cnt);
  k_moe_off<<<1, 64, 0, stream>>>(cnt, offs, tiles);
  k_moe_assign<<<32, 256, 0, stream>>>(texp, twt, offs, slot_token, slot_wt);
  k_moe_up<<<dim3(16, MAXTILES), 256, 0, stream>>>(h2b, WT, cnt, offs, tiles, slot_token, act);
  k_wT<0><<<dim3(16, 16, 32), 256, 0, stream>>>(W_down, WT, nullptr, 1024);  // reuse WT buffer
  k_moe_down<<<dim3(8, MAXTILES), 256, 0, stream>>>(act, WT, cnt, offs, tiles, slot_token, slot_wt, out);
}

// Round 13
// 418.762 us; speedup vs baseline: 1.1330x; 1.1330x over previous
//
#include <hip/hip_runtime.h>
#include <hip/hip_bf16.h>

#define NEx 32
#define QKVN 1536
#define MAXTILES 96

typedef __attribute__((ext_vector_type(4))) float f32x4_t;
typedef __attribute__((ext_vector_type(8))) __bf16 bf16x8_t;

__device__ __forceinline__ unsigned short f2bfu(float f) {
  union { float f; unsigned int u; } a; a.f = f;
  unsigned int r = a.u + 0x7fffu + ((a.u >> 16) & 1u);
  return (unsigned short)(r >> 16);
}
__device__ __forceinline__ float bf2f(unsigned short u) {
  union { unsigned int u; float f; } a; a.u = ((unsigned int)u) << 16; return a.f;
}
__device__ __forceinline__ uint2 pack4u(unsigned short a, unsigned short b,
                                        unsigned short c, unsigned short d) {
  return make_uint2((unsigned int)a | ((unsigned int)b << 16),
                    (unsigned int)c | ((unsigned int)d << 16));
}
__device__ __forceinline__ void split2(float v, unsigned short& hi, unsigned short& lo) {
  hi = f2bfu(v);
  lo = f2bfu(v - bf2f(hi));
}
// async global->LDS, 16B per lane; lds dest = wave-uniform base + lane*16
typedef const __attribute__((address_space(1))) void* gas_t;
typedef __attribute__((address_space(3))) void* las_t;
__device__ __forceinline__ void gl16(const void* g, void* l) {
  __builtin_amdgcn_global_load_lds((gas_t)g, (las_t)l, 16, 0, 0);
}

// ---------- weight transpose(+convert) prepass: fp32 [E][K=1024][N] -> bf16 [E][N][1024] ----------
template<int SPLIT>
__global__ __launch_bounds__(256) void k_wT(const float* __restrict__ in,
    unsigned short* __restrict__ outh, unsigned short* __restrict__ outl, int N) {
  __shared__ float T[64][68];
  int k0 = blockIdx.x * 64, n0 = blockIdx.y * 64, e = blockIdx.z;
  const float* src = in + (size_t)e * 1024 * N;
  int t = threadIdx.x;
  int rk = t >> 2, c4 = (t & 3) * 4;
#pragma unroll
  for (int j = 0; j < 4; ++j) {
    int col = c4 + j * 16;
    f32x4_t v = *(const f32x4_t*)(src + (size_t)(k0 + rk) * N + n0 + col);
    *(f32x4_t*)&T[rk][col] = v;
  }
  __syncthreads();
  int nn = t >> 2, kc0 = (t & 3) * 16;
  size_t orow = ((size_t)e * N + n0 + nn) * 1024 + k0;
#pragma unroll
  for (int j = 0; j < 2; ++j) {
    int kc = kc0 + j * 8;
    unsigned short hi[8], lo[8];
#pragma unroll
    for (int q = 0; q < 8; ++q) split2(T[kc + q][nn], hi[q], lo[q]);
    uint2 a = pack4u(hi[0], hi[1], hi[2], hi[3]);
    uint2 b = pack4u(hi[4], hi[5], hi[6], hi[7]);
    *(uint4*)(outh + orow + kc) = make_uint4(a.x, a.y, b.x, b.y);
    if (SPLIT) {
      uint2 c = pack4u(lo[0], lo[1], lo[2], lo[3]);
      uint2 d = pack4u(lo[4], lo[5], lo[6], lo[7]);
      *(uint4*)(outl + orow + kc) = make_uint4(c.x, c.y, d.x, d.y);
    }
  }
}

// ---------- RMSNorm -> bf16 hi/lo planes ----------
__global__ __launch_bounds__(256) void k_rmsnorm_s(const float* __restrict__ x,
    const float* __restrict__ w, unsigned short* __restrict__ ph, unsigned short* __restrict__ pl) {
  int row = blockIdx.x, tid = threadIdx.x;
  f32x4_t v = *(const f32x4_t*)(x + (size_t)row * 1024 + tid * 4);
  float ss = v.x * v.x + v.y * v.y + v.z * v.z + v.w * v.w;
#pragma unroll
  for (int o = 32; o > 0; o >>= 1) ss += __shfl_xor(ss, o);
  __shared__ float red[4];
  if ((tid & 63) == 0) red[tid >> 6] = ss;
  __syncthreads();
  float sc = rsqrtf((red[0] + red[1] + red[2] + red[3]) * (1.f / 1024.f) + 1e-5f);
  const float* wr = w + tid * 4;
  ushort4 h4, l4;
  split2(v.x * sc * wr[0], h4.x, l4.x);
  split2(v.y * sc * wr[1], h4.y, l4.y);
  split2(v.z * sc * wr[2], h4.z, l4.z);
  split2(v.w * sc * wr[3], h4.w, l4.w);
  *(ushort4*)(ph + (size_t)row * 1024 + tid * 4) = h4;
  *(ushort4*)(pl + (size_t)row * 1024 + tid * 4) = l4;
}

// ---------- RMSNorm -> fp32 + bf16; also seeds out = x1 ----------
__global__ __launch_bounds__(256) void k_rmsnorm_f(const float* __restrict__ x,
    const float* __restrict__ w, float* __restrict__ outf, unsigned short* __restrict__ outb,
    float* __restrict__ out) {
  int row = blockIdx.x, tid = threadIdx.x;
  f32x4_t v = *(const f32x4_t*)(x + (size_t)row * 1024 + tid * 4);
  *(f32x4_t*)(out + (size_t)row * 1024 + tid * 4) = v;   // out = x1; moe_down accumulates
  float ss = v.x * v.x + v.y * v.y + v.z * v.z + v.w * v.w;
#pragma unroll
  for (int o = 32; o > 0; o >>= 1) ss += __shfl_xor(ss, o);
  __shared__ float red[4];
  if ((tid & 63) == 0) red[tid >> 6] = ss;
  __syncthreads();
  float sc = rsqrtf((red[0] + red[1] + red[2] + red[3]) * (1.f / 1024.f) + 1e-5f);
  const float* wr = w + tid * 4;
  f32x4_t o4;
  o4.x = v.x * sc * wr[0]; o4.y = v.y * sc * wr[1];
  o4.z = v.z * sc * wr[2]; o4.w = v.w * sc * wr[3];
  *(f32x4_t*)(outf + (size_t)row * 1024 + tid * 4) = o4;
  ushort4 b4;
  b4.x = f2bfu(o4.x); b4.y = f2bfu(o4.y); b4.z = f2bfu(o4.z); b4.w = f2bfu(o4.w);
  *(ushort4*)(outb + (size_t)row * 1024 + tid * 4) = b4;
}

// ---------- split-plane GEMM (fp32-accurate): C = A @ B^T + bias (+res) ----------
// 64x64 tile, 4 waves each 32x32 quadrant; grid 2x denser than 64x128 for latency hiding.
template<int RES>
__global__ __launch_bounds__(256) void k_gemm_s(
    const unsigned short* __restrict__ Ahg, const unsigned short* __restrict__ Alg,
    const unsigned short* __restrict__ BhT, const unsigned short* __restrict__ BlT,
    const float* __restrict__ bias, const float* __restrict__ res,
    float* __restrict__ C, int N) {
  __shared__ unsigned short Ah[64 * 32], Al[64 * 32], Bh[64 * 32], Bl[64 * 32];
  int tid = threadIdx.x, lane = tid & 63, w = tid >> 6;
  int m0 = blockIdx.y * 64, n0 = blockIdx.x * 64;
  int wm = (w >> 1) * 32, wn = (w & 1) * 32;
  int rl = lane >> 2, koff = (lane & 3) * 8;
  const unsigned short* agh = Ahg + (size_t)(m0 + w * 16 + rl) * 1024 + koff;
  const unsigned short* agl = Alg + (size_t)(m0 + w * 16 + rl) * 1024 + koff;
  const unsigned short* bgh = BhT + (size_t)(n0 + w * 16 + rl) * 1024 + koff;
  const unsigned short* bgl = BlT + (size_t)(n0 + w * 16 + rl) * 1024 + koff;
  f32x4_t acc[2][2];
#pragma unroll
  for (int i = 0; i < 2; ++i)
#pragma unroll
    for (int j = 0; j < 2; ++j) acc[i][j] = (f32x4_t){0.f, 0.f, 0.f, 0.f};
  int fr = lane & 15, fc = (lane >> 4) * 8;
  for (int k0 = 0; k0 < 1024; k0 += 32) {
    gl16(agh + k0, (char*)Ah + w * 1024);
    gl16(agl + k0, (char*)Al + w * 1024);
    gl16(bgh + k0, (char*)Bh + w * 1024);
    gl16(bgl + k0, (char*)Bl + w * 1024);
    __syncthreads();
    bf16x8_t fah[2], fal[2], fbh[2], fbl[2];
#pragma unroll
    for (int mi = 0; mi < 2; ++mi) {
      fah[mi] = *(const bf16x8_t*)(Ah + (wm + mi * 16 + fr) * 32 + fc);
      fal[mi] = *(const bf16x8_t*)(Al + (wm + mi * 16 + fr) * 32 + fc);
    }
#pragma unroll
    for (int nj = 0; nj < 2; ++nj) {
      fbh[nj] = *(const bf16x8_t*)(Bh + (wn + nj * 16 + fr) * 32 + fc);
      fbl[nj] = *(const bf16x8_t*)(Bl + (wn + nj * 16 + fr) * 32 + fc);
    }
#pragma unroll
    for (int mi = 0; mi < 2; ++mi)
#pragma unroll
      for (int nj = 0; nj < 2; ++nj) {
        acc[mi][nj] = __builtin_amdgcn_mfma_f32_16x16x32_bf16(fah[mi], fbh[nj], acc[mi][nj], 0, 0, 0);
        acc[mi][nj] = __builtin_amdgcn_mfma_f32_16x16x32_bf16(fah[mi], fbl[nj], acc[mi][nj], 0, 0, 0);
        acc[mi][nj] = __builtin_amdgcn_mfma_f32_16x16x32_bf16(fal[mi], fbh[nj], acc[mi][nj], 0, 0, 0);
      }
    __syncthreads();
  }
  int frow = (lane >> 4) * 4;
#pragma unroll
  for (int mi = 0; mi < 2; ++mi)
#pragma unroll
    for (int nj = 0; nj < 2; ++nj) {
      int col = n0 + wn + nj * 16 + fr;
      float bv = bias[col];
#pragma unroll
      for (int r = 0; r < 4; ++r) {
        int row = m0 + wm + mi * 16 + frow + r;
        float v = acc[mi][nj][r] + bv;
        if (RES) v += res[(size_t)row * N + col];
        C[(size_t)row * N + col] = v;
      }
    }
}

// ---------- RoPE in-place ----------
__global__ __launch_bounds__(256) void k_rope(float* __restrict__ qkv) {
  int idx = blockIdx.x * 256 + threadIdx.x;
  int i = idx & 31;
  int r5 = idx >> 5;
  int hd = r5 % 20, t = r5 / 20;
  int col = (hd < 16) ? hd * 64 : 1024 + (hd - 16) * 64;
  float* p = qkv + (size_t)t * QKVN + col + 2 * i;
  float2 v = *(float2*)p;
  float invf = exp2f(-(float)i * (17.194602975157967f / 32.f));
  float ang = ((float)t * (1.f / 32.f)) * invf;
  float s, c;
  sincosf(ang, &s, &c);
  float2 o; o.x = v.x * c - v.y * s; o.y = v.x * s + v.y * c;
  *(float2*)p = o;
}

// ---------- sliding-window attention with sink; fused 4-query loops, wave-private softmax ----------
__global__ __launch_bounds__(256) void k_attn(const float* __restrict__ qkv,
    const float* __restrict__ sink, unsigned short* __restrict__ yh,
    unsigned short* __restrict__ yl) {
  __shared__ float Kl[72 * 65];
  __shared__ float Vl[72 * 64];
  __shared__ float ql[16][64];
  __shared__ float pl[4][4][128];   // [wave][qq][slot] — wave-private, no barriers needed
  int i0 = blockIdx.x * 16, hh = blockIdx.y;
  int g = hh >> 2;
  int jb = i0 - 128; if (jb < 0) jb = 0;
  int nk = i0 + 16 - jb;
  int tid = threadIdx.x, wid = tid >> 6, lane = tid & 63;
  {
    int r = tid >> 4, d4 = (tid & 15) * 4;
    *(f32x4_t*)&ql[r][d4] = *(const f32x4_t*)(qkv + (size_t)(i0 + r) * QKVN + hh * 64 + d4);
  }
  float sk = sink[hh];
  float m_[4], s_[4], y_[4];
#pragma unroll
  for (int qq = 0; qq < 4; ++qq) { m_[qq] = sk; s_[qq] = 0.f; y_[qq] = 0.f; }
  int nch = (nk + 71) / 72;
  int cbase = 0;
  int qb = wid * 4;
  for (int ch = 0; ch < nch; ++ch) {
    int csz = nk - cbase; if (csz > 72) csz = 72;
    __syncthreads();
    for (int id = tid; id < csz * 16; id += 256) {
      int c = id >> 4, d4 = (id & 15) * 4;
      const float* kp = qkv + (size_t)(jb + cbase + c) * QKVN + 1024 + g * 64 + d4;
      *(f32x4_t*)&Kl[c * 65 + d4] = *(const f32x4_t*)kp;
      *(f32x4_t*)&Vl[c * 64 + d4] = *(const f32x4_t*)(kp + 256);
    }
    __syncthreads();
    int s1 = lane + 64;
    int r1 = (s1 < csz) ? s1 : (csz - 1);
    const float* k0p = Kl + lane * 65;
    const float* k1p = Kl + r1 * 65;
    float a0[4] = {0.f, 0.f, 0.f, 0.f}, a1[4] = {0.f, 0.f, 0.f, 0.f};
#pragma unroll 4
    for (int d = 0; d < 64; ++d) {
      float k0 = k0p[d], k1 = k1p[d];
#pragma unroll
      for (int qq = 0; qq < 4; ++qq) {
        float qd = ql[qb + qq][d];
        a0[qq] += qd * k0;
        a1[qq] += qd * k1;
      }
    }
    int c0 = cbase + lane, c1 = cbase + s1;
    float fac_[4];
#pragma unroll
    for (int qq = 0; qq < 4; ++qq) {
      int cm = i0 + qb + qq - jb;
      bool ok0 = (lane < csz) && (c0 <= cm) && (c0 >= cm - 128);
      bool ok1 = (s1 < csz) && (c1 <= cm) && (c1 >= cm - 128);
      float l0 = ok0 ? a0[qq] * 0.125f : -1e30f;
      float l1 = ok1 ? a1[qq] * 0.125f : -1e30f;
      float mc = fmaxf(l0, l1);
#pragma unroll
      for (int o = 32; o > 0; o >>= 1) mc = fmaxf(mc, __shfl_xor(mc, o));
      float mo = m_[qq];
      float mn = fmaxf(mo, mc);
      float fac = __expf(mo - mn);
      float p0 = __expf(l0 - mn), p1 = __expf(l1 - mn);
      float ps = p0 + p1;
#pragma unroll
      for (int o = 32; o > 0; o >>= 1) ps += __shfl_xor(ps, o);
      m_[qq] = mn;
      s_[qq] = s_[qq] * fac + ps;
      pl[wid][qq][lane] = p0;
      pl[wid][qq][s1] = p1;
      fac_[qq] = fac;
    }
#pragma unroll
    for (int qq = 0; qq < 4; ++qq) y_[qq] *= fac_[qq];
    for (int s = 0; s < csz; ++s) {
      float v = Vl[s * 64 + lane];
      y_[0] += pl[wid][0][s] * v;
      y_[1] += pl[wid][1][s] * v;
      y_[2] += pl[wid][2][s] * v;
      y_[3] += pl[wid][3][s] * v;
    }
    cbase += csz;
  }
#pragma unroll
  for (int qq = 0; qq < 4; ++qq) {
    float inv = 1.f / (s_[qq] + __expf(sk - m_[qq]));
    int i = i0 + qb + qq;
    unsigned short hi, lo;
    split2(y_[qq] * inv, hi, lo);
    yh[(size_t)i * 1024 + hh * 64 + lane] = hi;
    yl[(size_t)i * 1024 + hh * 64 + lane] = lo;
  }
}

// ---------- gate + top4 + softmax (fp32) ----------
__global__ __launch_bounds__(64) void k_gate(const float* __restrict__ h2f,
    const float* __restrict__ gw, const float* __restrict__ gb,
    int* __restrict__ texp, float* __restrict__ twt) {
  int t = blockIdx.x, l = threadIdx.x;
  int e = l & 31, half = l >> 5;
  const float* hr = h2f + (size_t)t * 1024 + half * 512;
  const float* wp = gw + (size_t)half * 512 * 32 + e;
  float s = 0;
  for (int d = 0; d < 512; ++d) s += hr[d] * wp[(size_t)d * 32];
  s += __shfl_xor(s, 32);
  __shared__ float gl[32];
  if (l < 32) gl[l] = s + gb[e];
  __syncthreads();
  if (l == 0) {
    int bi[4]; float bv[4];
    for (int j = 0; j < 4; ++j) {
      int mi_ = 0; float mv = gl[0];
      for (int q = 1; q < 32; ++q) if (gl[q] > mv) { mv = gl[q]; mi_ = q; }
      bi[j] = mi_; bv[j] = mv; gl[mi_] = -1e30f;
    }
    float mx = bv[0], sum = 0, wv[4];
    for (int j = 0; j < 4; ++j) { wv[j] = __expf(bv[j] - mx); sum += wv[j]; }
    float inv = 1.f / sum;
    for (int j = 0; j < 4; ++j) { texp[t * 4 + j] = bi[j]; twt[t * 4 + j] = wv[j] * inv; }
  }
}

// ---------- deterministic expert bucketing ----------
__global__ __launch_bounds__(256) void k_moe_count(const int* __restrict__ texp, int* __restrict__ cnt) {
  int e = blockIdx.x, tid = threadIdx.x;
  int c = 0;
  for (int i = tid; i < 8192; i += 256) c += (texp[i] == e);
#pragma unroll
  for (int o = 32; o > 0; o >>= 1) c += __shfl_xor(c, o);
  __shared__ int red[4];
  if ((tid & 63) == 0) red[tid >> 6] = c;
  __syncthreads();
  if (tid == 0) cnt[e] = red[0] + red[1] + red[2] + red[3];
}

__global__ void k_moe_off(const int* __restrict__ cnt, int* __restrict__ off,
                          int* __restrict__ tiles) {
  if (threadIdx.x == 0) {
    int s = 0, t = 0;
    for (int e = 0; e < NEx; ++e) {
      off[e] = s;
      int nt = (cnt[e] + 127) >> 7;
      for (int j = 0; j < nt; ++j) tiles[t++] = e | (j << 8);
      s += cnt[e];
    }
    for (; t < MAXTILES; ++t) tiles[t] = -1;
  }
}

__global__ __launch_bounds__(256) void k_moe_assign(const int* __restrict__ texp,
    const float* __restrict__ twt, const int* __restrict__ off,
    int* __restrict__ slot_token, float* __restrict__ slot_wt) {
  int e = blockIdx.x, tid = threadIdx.x;
  int b0 = tid * 32;
  int c = 0;
  for (int i = 0; i < 32; ++i) c += (texp[b0 + i] == e);
  __shared__ int pre[256];
  pre[tid] = c;
  __syncthreads();
  for (int d = 1; d < 256; d <<= 1) {
    int v = (tid >= d) ? pre[tid - d] : 0;
    __syncthreads();
    pre[tid] += v;
    __syncthreads();
  }
  int run = off[e] + pre[tid] - c;
  for (int i = 0; i < 32; ++i) {
    int idx = b0 + i;
    if (texp[idx] == e) {
      slot_token[run] = idx >> 2;
      slot_wt[run] = twt[idx];
      ++run;
    }
  }
}

// ---------- MoE up: bf16 x bf16^T, gl16 staging (round-10 structure) ----------
__global__ __launch_bounds__(256) void k_moe_up(const unsigned short* __restrict__ h2b,
    const unsigned short* __restrict__ WupT, const int* __restrict__ cnt,
    const int* __restrict__ off, const int* __restrict__ tiles,
    const int* __restrict__ slot_token, unsigned short* __restrict__ act) {
  int code = tiles[blockIdx.y];
  if (code < 0) return;
  int e = code & 255;
  int m0 = (code >> 8) << 7;
  int ne = cnt[e];
  int n0 = blockIdx.x * 64;
  int base = off[e];
  __shared__ unsigned short Asm[128 * 32];
  __shared__ unsigned short Bsm[128 * 32];
  int tid = threadIdx.x, lane = tid & 63, w = tid >> 6;
  int rl = lane >> 2, koff = (lane & 3) * 8;
  const unsigned short* ag[2];
  const unsigned short* bg[2];
#pragma unroll
  for (int i = 0; i < 2; ++i) {
    int row = (w * 2 + i) * 16 + rl;
    int tok = (m0 + row < ne) ? slot_token[base + m0 + row] : 0;
    ag[i] = h2b + (size_t)tok * 1024 + koff;
    int grow = (row < 64) ? (n0 + row) : (1024 + n0 + row - 64);
    bg[i] = WupT + (size_t)e * 2048 * 1024 + (size_t)grow * 1024 + koff;
  }
  f32x4_t acc[2][8];
#pragma unroll
  for (int i = 0; i < 2; ++i)
#pragma unroll
    for (int j = 0; j < 8; ++j) acc[i][j] = (f32x4_t){0.f, 0.f, 0.f, 0.f};
  int fr = lane & 15, fc = (lane >> 4) * 8;
  for (int k0 = 0; k0 < 1024; k0 += 32) {
    gl16(ag[0] + k0, (char*)Asm + (w * 2 + 0) * 1024);
    gl16(ag[1] + k0, (char*)Asm + (w * 2 + 1) * 1024);
    gl16(bg[0] + k0, (char*)Bsm + (w * 2 + 0) * 1024);
    gl16(bg[1] + k0, (char*)Bsm + (w * 2 + 1) * 1024);
    __syncthreads();
    bf16x8_t af[2], bfr[8];
#pragma unroll
    for (int mi = 0; mi < 2; ++mi)
      af[mi] = *(const bf16x8_t*)(Asm + (w * 32 + mi * 16 + fr) * 32 + fc);
#pragma unroll
    for (int nj = 0; nj < 8; ++nj)
      bfr[nj] = *(const bf16x8_t*)(Bsm + (nj * 16 + fr) * 32 + fc);
#pragma unroll
    for (int mi = 0; mi < 2; ++mi)
#pragma unroll
      for (int nj = 0; nj < 8; ++nj)
        acc[mi][nj] = __builtin_amdgcn_mfma_f32_16x16x32_bf16(af[mi], bfr[nj], acc[mi][nj], 0, 0, 0);
    __syncthreads();
  }
  int frow = (lane >> 4) * 4;
#pragma unroll
  for (int mi = 0; mi < 2; ++mi)
#pragma unroll
    for (int r = 0; r < 4; ++r) {
      int row = m0 + w * 32 + mi * 16 + frow + r;
      if (row < ne) {
#pragma unroll
        for (int nj = 0; nj < 4; ++nj) {
          float u = acc[mi][nj][r];
          float gg = acc[mi][nj + 4][r];
          float sig = 1.f / (1.f + __expf(-gg));
          act[(size_t)(base + row) * 1024 + n0 + nj * 16 + fr] = f2bfu(u * gg * sig);
        }
      }
    }
}

// ---------- MoE down: bf16 x bf16^T, gl16 staging, atomic scatter into OUT ----------
__global__ __launch_bounds__(256) void k_moe_down(const unsigned short* __restrict__ act,
    const unsigned short* __restrict__ WdnT, const int* __restrict__ cnt,
    const int* __restrict__ off, const int* __restrict__ tiles,
    const int* __restrict__ slot_token, const float* __restrict__ slot_wt,
    float* __restrict__ out) {
  int code = tiles[blockIdx.y];
  if (code < 0) return;
  int e = code & 255;
  int m0 = (code >> 8) << 7;
  int ne = cnt[e];
  int n0 = blockIdx.x * 128;
  int base = off[e];
  __shared__ unsigned short Asm[128 * 32];
  __shared__ unsigned short Bsm[128 * 32];
  int tid = threadIdx.x, lane = tid & 63, w = tid >> 6;
  int wm = (w >> 1) * 64, wn = (w & 1) * 64;
  int rl = lane >> 2, koff = (lane & 3) * 8;
  const unsigned short* ag[2];
  const unsigned short* bg[2];
#pragma unroll
  for (int i = 0; i < 2; ++i) {
    int row = (w * 2 + i) * 16 + rl;
    ag[i] = act + (size_t)(base + m0 + row) * 1024 + koff;  // act padded, OOB rows safe
    bg[i] = WdnT + (size_t)e * 1024 * 1024 + (size_t)(n0 + row) * 1024 + koff;
  }
  f32x4_t acc[4][4];
#pragma unroll
  for (int i = 0; i < 4; ++i)
#pragma unroll
    for (int j = 0; j < 4; ++j) acc[i][j] = (f32x4_t){0.f, 0.f, 0.f, 0.f};
  int fr = lane & 15, fc = (lane >> 4) * 8;
  for (int k0 = 0; k0 < 1024; k0 += 32) {
    gl16(ag[0] + k0, (char*)Asm + (w * 2 + 0) * 1024);
    gl16(ag[1] + k0, (char*)Asm + (w * 2 + 1) * 1024);
    gl16(bg[0] + k0, (char*)Bsm + (w * 2 + 0) * 1024);
    gl16(bg[1] + k0, (char*)Bsm + (w * 2 + 1) * 1024);
    __syncthreads();
    bf16x8_t af[4], bfr[4];
#pragma unroll
    for (int mi = 0; mi < 4; ++mi)
      af[mi] = *(const bf16x8_t*)(Asm + (wm + mi * 16 + fr) * 32 + fc);
#pragma unroll
    for (int nj = 0; nj < 4; ++nj)
      bfr[nj] = *(const bf16x8_t*)(Bsm + (wn + nj * 16 + fr) * 32 + fc);
#pragma unroll
    for (int mi = 0; mi < 4; ++mi)
#pragma unroll
      for (int nj = 0; nj < 4; ++nj)
        acc[mi][nj] = __builtin_amdgcn_mfma_f32_16x16x32_bf16(af[mi], bfr[nj], acc[mi][nj], 0, 0, 0);
    __syncthreads();
  }
  int frow = (lane >> 4) * 4;
#pragma unroll
  for (int mi = 0; mi < 4; ++mi)
#pragma unroll
    for (int r = 0; r < 4; ++r) {
      int row = m0 + wm + mi * 16 + frow + r;
      if (row < ne) {
        int slot = base + row;
        int token = slot_token[slot];
        float wt = slot_wt[slot];
#pragma unroll
        for (int nj = 0; nj < 4; ++nj) {
          int col = n0 + wn + nj * 16 + fr;
          atomicAdd(&out[(size_t)token * 1024 + col], wt * acc[mi][nj][r]);
        }
      }
    }
}

extern "C" void kernel_launch(void* const* d_in, const int* in_sizes, int n_in,
                              void* d_out, int out_size, void* d_ws, size_t ws_size,
                              hipStream_t stream) {
  const float* x           = (const float*)d_in[0];
  const float* attn_norm_w = (const float*)d_in[1];
  const float* ffn_norm_w  = (const float*)d_in[2];
  const float* qkv_w       = (const float*)d_in[3];
  const float* qkv_b       = (const float*)d_in[4];
  const float* proj_w      = (const float*)d_in[5];
  const float* proj_b      = (const float*)d_in[6];
  const float* attn_sink   = (const float*)d_in[7];
  const float* gate_w      = (const float*)d_in[8];
  const float* gate_b      = (const float*)d_in[9];
  const float* W_up        = (const float*)d_in[10];
  const float* W_down      = (const float*)d_in[11];
  float* out = (float*)d_out;

  char* ws = (char*)d_ws;
  size_t o = 0;
  auto alloc = [&](size_t bytes) -> void* {
    void* p = ws + o;
    o = (o + bytes + 255) & ~(size_t)255;
    return p;
  };
  unsigned short* WT      = (unsigned short*)alloc((size_t)32 * 2048 * 1024 * 2); // WupT then WdnT
  unsigned short* qkvThi  = (unsigned short*)alloc((size_t)1536 * 1024 * 2);
  unsigned short* qkvTlo  = (unsigned short*)alloc((size_t)1536 * 1024 * 2);
  unsigned short* projThi = (unsigned short*)alloc((size_t)1024 * 1024 * 2);
  unsigned short* projTlo = (unsigned short*)alloc((size_t)1024 * 1024 * 2);
  unsigned short* pAhi    = (unsigned short*)alloc((size_t)2048 * 1024 * 2);  // h planes, then y planes
  unsigned short* pAlo    = (unsigned short*)alloc((size_t)2048 * 1024 * 2);
  float* qkv              = (float*)alloc((size_t)2048 * 1536 * 4);           // later h2f(8MB)+h2b(4MB)
  float* x1               = (float*)alloc((size_t)2048 * 1024 * 4);
  unsigned short* act     = (unsigned short*)alloc((size_t)(8192 + 128) * 1024 * 2);
  int* texp               = (int*)alloc(8192 * 4);
  float* twt              = (float*)alloc(8192 * 4);
  int* cnt                = (int*)alloc(256);
  int* offs               = (int*)alloc(256);
  int* tiles              = (int*)alloc(MAXTILES * 4);
  int* slot_token         = (int*)alloc(8192 * 4);
  float* slot_wt          = (float*)alloc(8192 * 4);
  float* h2f              = qkv;                                   // qkv dead after attn
  unsigned short* h2b     = (unsigned short*)(qkv + (size_t)2048 * 1024);

  // weight prepass (qkv/proj split planes; W_up bf16 transposed)
  k_wT<1><<<dim3(16, 24, 1), 256, 0, stream>>>(qkv_w, qkvThi, qkvTlo, 1536);
  k_wT<1><<<dim3(16, 16, 1), 256, 0, stream>>>(proj_w, projThi, projTlo, 1024);
  k_wT<0><<<dim3(16, 32, 32), 256, 0, stream>>>(W_up, WT, nullptr, 2048);

  k_rmsnorm_s<<<2048, 256, 0, stream>>>(x, attn_norm_w, pAhi, pAlo);
  k_gemm_s<0><<<dim3(24, 32), 256, 0, stream>>>(pAhi, pAlo, qkvThi, qkvTlo, qkv_b, nullptr, qkv, 1536);
  k_rope<<<5120, 256, 0, stream>>>(qkv);
  k_attn<<<dim3(128, 16), 256, 0, stream>>>(qkv, attn_sink, pAhi, pAlo);
  k_gemm_s<1><<<dim3(16, 32), 256, 0, stream>>>(pAhi, pAlo, projThi, projTlo, proj_b, x, x1, 1024);
  k_rmsnorm_f<<<2048, 256, 0, stream>>>(x1, ffn_norm_w, h2f, h2b, out);
  k_gate<<<2048, 64, 0, stream>>>(h2f, gate_w, gate_b, texp, twt);
  k_moe_count<<<32, 256, 0, stream>>>(texp, cnt);
  k_moe_off<<<1, 64, 0, stream>>>(cnt, offs, tiles);
  k_moe_assign<<<32, 256, 0, stream>>>(texp, twt, offs, slot_token, slot_wt);
  k_moe_up<<<dim3(16, MAXTILES), 256, 0, stream>>>(h2b, WT, cnt, offs, tiles, slot_token, act);
  k_wT<0><<<dim3(16, 16, 32), 256, 0, stream>>>(W_down, WT, nullptr, 1024);  // reuse WT buffer
  k_moe_down<<<dim3(8, MAXTILES), 256, 0, stream>>>(act, WT, cnt, offs, tiles, slot_token, slot_wt, out);
}